// Round 5
// baseline (231.808 us; speedup 1.0000x reference)
//
#include <hip/hip_runtime.h>
#include <hip/hip_bf16.h>

#define B_   4
#define C_   512
#define C8_  64
#define HW_  4096

typedef short bf16x8 __attribute__((ext_vector_type(8)));
typedef float f32x4  __attribute__((ext_vector_type(4)));

__device__ __forceinline__ unsigned short f2bf(float f) {
  union { unsigned int i; float f; } x; x.f = f;
  unsigned int r = x.i + 0x7fffu + ((x.i >> 16) & 1u);   // RNE
  return (unsigned short)(r >> 16);
}

// packed f32x2 -> bf16x2 (RNE), single VALU op; no builtin on gfx950
__device__ __forceinline__ unsigned int cvtpk(float lo, float hi) {
  unsigned int r;
  asm("v_cvt_pk_bf16_f32 %0, %1, %2" : "=v"(r) : "v"(lo), "v"(hi));
  return r;
}

// 2^x, single transcendental op
__device__ __forceinline__ float fexp2(float x) {
  float r;
  asm("v_exp_f32 %0, %1" : "=v"(r) : "v"(x));
  return r;
}

#define MFMA(a, b, c) __builtin_amdgcn_mfma_f32_16x16x32_bf16((a), (b), (c), 0, 0, 0)

#define LOG2E 1.44269504f
#define NEG20LOG2E -28.8539008f   // -20*log2(e): folded softmax shift (C-init)

// ---------------------------------------------------------------------------
// Fragment-major workspace layouts (R8): every flash global load is one
// fully-contiguous 1KB wave load (lane*16B).
//  Q/K (64-col):  idx = (b*512 + (row>>4)*2 + (col>>5))*512
//                     + ((col>>3)&3)*128 + (row&15)*8 + (col&7)
//  V ([ch][m]):   idx = ((b*32 + (ch>>4))*128 + (m>>5))*512
//                     + ((m>>3)&3)*128 + (ch&15)*8 + (m&7)
//  Q is pre-scaled by log2e (flash uses v_exp_f32 with C-init -20*log2e).
// ---------------------------------------------------------------------------

// ---------------------------------------------------------------------------
// proj R10->R11: MERGED. One block per (m-tile, b) = 256 blocks = 1/CU,
// 640 threads (10 waves). Per kb, LDS holds ALL 640 W rows (Q|K|V) + the
// fe^T and total^T tiles -- the transpose is done ONCE (was 5x: K + 4 V
// chunks each re-read + re-transposed fe) and W is staged once per m-tile
// (was once per 64-m-tile *per y-chunk*). Wave w owns output rows
// [w*64, w*64+64): wave0=Q (from total^T), wave1=K, waves2-9=V.
// LDS 110.6 KB -> 1 block/CU. Traffic: fe+total read once from HBM (64MB),
// W ~1.25MB/block from XCD L2.
// ---------------------------------------------------------------------------
__global__ __launch_bounds__(640) void proj_kernel(
    const float* __restrict__ total, const float* __restrict__ fe,
    const float* __restrict__ Wq, const float* __restrict__ bq,
    const float* __restrict__ Wk, const float* __restrict__ bk,
    const float* __restrict__ Wv, const float* __restrict__ bv,
    const float* __restrict__ ht, const float* __restrict__ wt,
    unsigned short* __restrict__ Qh, unsigned short* __restrict__ Kh,
    unsigned short* __restrict__ Vn) {
  __shared__ __align__(16) unsigned short Ws[640 * 72];   // rows: 0-63 Wq | 64-127 Wk | 128-639 Wv (92.2 KB)
  __shared__ __align__(16) unsigned short Xf[64 * 72];    // fe^T    [m][c] (9.2 KB)
  __shared__ __align__(16) unsigned short Xt[64 * 72];    // total^T [m][c] (9.2 KB)

  const int t = threadIdx.x;
  const int b = blockIdx.y;
  const int x = blockIdx.x;            // m-tile (= image row h, since W=64)
  const int m0 = x * 64;
  const int lane = t & 63, w = t >> 6, ln = lane & 15, quad = lane >> 4;

  // W staging coords: c4 = (i*640+t)&15 = t&15 (640 % 16 == 0), o = i*40 + t>>4
  const int c4 = t & 15;
  const int orow = t >> 4;             // 0..39

  f32x4 acc[4][4];                     // [ct(ch-tile)][mt(m-tile)]
#pragma unroll
  for (int ct = 0; ct < 4; ++ct)
#pragma unroll
    for (int mt = 0; mt < 4; ++mt) acc[ct][mt] = f32x4{0.f, 0.f, 0.f, 0.f};

  for (int kb = 0; kb < 8; ++kb) {
    const int c0 = kb * 64;
    // ---- stage W: 640 rows x 64 c, 16 tasks/thread ----
#pragma unroll
    for (int i = 0; i < 16; ++i) {
      const int o = i * 40 + orow;
      const float* src = (o < 64) ? &Wq[(size_t)o * C_]
                       : (o < 128) ? &Wk[(size_t)(o - 64) * C_]
                                   : &Wv[(size_t)(o - 128) * C_];
      f32x4 wv = *(const f32x4*)&src[c0 + c4 * 4];
      *(uint2*)&Ws[o * 72 + c4 * 4] =
          make_uint2(cvtpk(wv[0], wv[1]), cvtpk(wv[2], wv[3]));
    }
    // ---- stage X transposes: threads 0-255 -> fe^T, 256-511 -> total^T ----
    if (t < 512) {
      const int t2 = t & 255;
      const float* Xsrc = (t < 256) ? fe : total;
      unsigned short* Xdst = (t < 256) ? Xf : Xt;
      const int rc4 = t2 >> 4, mq = t2 & 15;
      f32x4 xv[4];
#pragma unroll
      for (int k = 0; k < 4; ++k)
        xv[k] = *(const f32x4*)&Xsrc[((size_t)b * C_ + c0 + rc4 * 4 + k) * HW_ + m0 + mq * 4];
#pragma unroll
      for (int j = 0; j < 4; ++j)
        *(uint2*)&Xdst[(mq * 4 + j) * 72 + rc4 * 4] =
            make_uint2(cvtpk(xv[0][j], xv[1][j]), cvtpk(xv[2][j], xv[3][j]));
    }
    __syncthreads();
    // ---- MFMA: wave w computes rows [w*64, w*64+64) x [m0, m0+64) ----
    const unsigned short* Xsel = (w == 0) ? Xt : Xf;
    bf16x8 aw[4][2], bx[4][2];
#pragma unroll
    for (int ct = 0; ct < 4; ++ct) {
      aw[ct][0] = *(const bf16x8*)&Ws[(w * 64 + ct * 16 + ln) * 72 + quad * 8];
      aw[ct][1] = *(const bf16x8*)&Ws[(w * 64 + ct * 16 + ln) * 72 + 32 + quad * 8];
    }
#pragma unroll
    for (int mt = 0; mt < 4; ++mt) {
      bx[mt][0] = *(const bf16x8*)&Xsel[(mt * 16 + ln) * 72 + quad * 8];
      bx[mt][1] = *(const bf16x8*)&Xsel[(mt * 16 + ln) * 72 + 32 + quad * 8];
    }
#pragma unroll
    for (int ct = 0; ct < 4; ++ct)
#pragma unroll
      for (int mt = 0; mt < 4; ++mt) {
        acc[ct][mt] = MFMA(aw[ct][0], bx[mt][0], acc[ct][mt]);
        acc[ct][mt] = MFMA(aw[ct][1], bx[mt][1], acc[ct][mt]);
      }
    __syncthreads();
  }

  // ---- epilogue: D row = ch (quad*4+r), D col = m (ln) ----
  if (w == 0) {
    // Q: out(m, o) fragment-major, val = (acc + bq)*log2e
#pragma unroll
    for (int ct = 0; ct < 4; ++ct)
#pragma unroll
      for (int mt = 0; mt < 4; ++mt)
#pragma unroll
        for (int r = 0; r < 4; ++r) {
          const int o = ct * 16 + quad * 4 + r;
          const float val = (acc[ct][mt][r] + bq[o]) * LOG2E;
          const size_t idx = ((size_t)b * 512 + (x * 4 + mt) * 2 + (ct >> 1)) * 512
                           + ((((ct & 1) << 1) | (quad >> 1))) * 128
                           + ln * 8 + ((quad & 1) << 2) + r;
          Qh[idx] = f2bf(val);
        }
  } else if (w == 1) {
    // K: + bias + positional (h = x, wloc = mt*16+ln)
#pragma unroll
    for (int ct = 0; ct < 4; ++ct)
#pragma unroll
      for (int mt = 0; mt < 4; ++mt)
#pragma unroll
        for (int r = 0; r < 4; ++r) {
          const int o = ct * 16 + quad * 4 + r;
          const float val = acc[ct][mt][r] + bk[o] + ht[o * 64 + x] + wt[o * 64 + mt * 16 + ln];
          const size_t idx = ((size_t)b * 512 + (x * 4 + mt) * 2 + (ct >> 1)) * 512
                           + ((((ct & 1) << 1) | (quad >> 1))) * 128
                           + ln * 8 + ((quad & 1) << 2) + r;
          Kh[idx] = f2bf(val);
        }
  } else {
    // V: ch = (w-2)*64 + ct*16 + quad*4 + r, fragment-major [ch][m]
#pragma unroll
    for (int ct = 0; ct < 4; ++ct) {
      const int cht = w * 4 - 8 + ct;
#pragma unroll
      for (int r = 0; r < 4; ++r) {
        const float bz = bv[cht * 16 + quad * 4 + r];
#pragma unroll
        for (int mt = 0; mt < 4; ++mt) {
          const size_t idx = (((size_t)b * 32 + cht) * 128 + (size_t)x * 2 + (mt >> 1)) * 512
                           + (((mt & 1) * 2) + (ln >> 3)) * 128 + (quad * 4 + r) * 8 + (ln & 7);
          Vn[idx] = f2bf(acc[ct][mt][r] + bz);
        }
      }
    }
  }
}

// ---------------------------------------------------------------------------
// flash (R10, unchanged): software-pipelined phase
//   {read P(t) frags || QK(t+1)+exp2+write P(t+1)}  then  PV(t).
// grid (512), 512 thr.
// ---------------------------------------------------------------------------
__global__ __launch_bounds__(512, 4) void flash_kernel(
    const unsigned short* __restrict__ Qh, const unsigned short* __restrict__ Kh,
    const unsigned short* __restrict__ Vn, const float* __restrict__ fe,
    const float* __restrict__ gamma, float* __restrict__ out) {
  __shared__ __align__(16) unsigned short Ps[2][64 * 64];    // 16 KB, swizzled
  __shared__ float Red[2][64];

  const int t = threadIdx.x;
  const int n = blockIdx.x;
  const int xcd = n & 7;                 // XCD swizzle: one (b, half) per XCD
  const int b = xcd & 3;
  const int ch0 = (xcd >> 2) * 256;
  const int q0 = (n >> 3) * 64;
  const int lane = t & 63, w = t >> 6, ln = lane & 15, quad = lane >> 4;
  const int qt = w & 3;                  // q sub-tile (16 rows) for QK^T
  const int kh = w >> 2;                 // k half (32 kpos) for QK^T
  const int swz = (ln & 7) << 4;         // P LDS XOR swizzle (byte)

  const unsigned short* Qb = Qh + (size_t)b * 512 * 512;
  const unsigned short* Kb = Kh + (size_t)b * 512 * 512;
  const unsigned short* Vbase = Vn + ((size_t)b * 32 + (ch0 >> 4)) * (128 * 512);

  // Q B-fragments (pre-scaled by log2e): contiguous 1KB wave loads
  const bf16x8 aq0 = *(const bf16x8*)&Qb[((size_t)((q0 >> 4) + qt) * 2 + 0) * 512 + lane * 8];
  const bf16x8 aq1 = *(const bf16x8*)&Qb[((size_t)((q0 >> 4) + qt) * 2 + 1) * 512 + lane * 8];

  const f32x4 CINIT = {NEG20LOG2E, NEG20LOG2E, NEG20LOG2E, NEG20LOG2E};

  float Sacc = 0.f;                      // partial softmax denom for q=qt*16+ln
  f32x4 acc[2][4];
#pragma unroll
  for (int mt = 0; mt < 2; ++mt)
#pragma unroll
    for (int nt = 0; nt < 4; ++nt) acc[mt][nt] = f32x4{0.f, 0.f, 0.f, 0.f};

  bf16x8 kf[2][2];   // [nt_k][c-half], this wave's kh half only
  bf16x8 vf[2][2];   // [mt][kc], ch rows w*32 + mt*16 + ln

  auto loadK = [&](int it) {
#pragma unroll
    for (int nt = 0; nt < 2; ++nt)
#pragma unroll
      for (int hf = 0; hf < 2; ++hf)
        kf[nt][hf] = *(const bf16x8*)&Kb[((size_t)(it * 4 + kh * 2 + nt) * 2 + hf) * 512 + lane * 8];
  };
  auto loadV = [&](int it) {
#pragma unroll
    for (int mt = 0; mt < 2; ++mt)
#pragma unroll
      for (int kc = 0; kc < 2; ++kc)
        vf[mt][kc] = *(const bf16x8*)&Vbase[(((size_t)(w * 2 + mt)) * 128 + it * 2 + kc) * 512 + lane * 8];
  };

  const int qrow = qt * 16 + ln;         // this lane's q column in E

  // exp2 + packed bf16 store of one 32k x 16q E tile + S accumulation
  auto writeP = [&](f32x4 e0, f32x4 e1, char* Pw) {
    const float p0 = fexp2(e0[0]), p1 = fexp2(e0[1]);
    const float p2 = fexp2(e0[2]), p3 = fexp2(e0[3]);
    Sacc += (p0 + p1) + (p2 + p3);
    *(uint2*)(Pw + ((qrow * 128 + kh * 64 + quad * 8) ^ swz)) =
        make_uint2(cvtpk(p0, p1), cvtpk(p2, p3));
    const float s0 = fexp2(e1[0]), s1 = fexp2(e1[1]);
    const float s2 = fexp2(e1[2]), s3 = fexp2(e1[3]);
    Sacc += (s0 + s1) + (s2 + s3);
    *(uint2*)(Pw + ((qrow * 128 + kh * 64 + 32 + quad * 8) ^ swz)) =
        make_uint2(cvtpk(s0, s1), cvtpk(s2, s3));
  };

  loadK(0);
  loadV(0);

  // ---- prologue: QK(0) -> P(0) ----
  {
    f32x4 e0 = MFMA(kf[0][0], aq0, CINIT);
    e0 = MFMA(kf[0][1], aq1, e0);
    f32x4 e1 = MFMA(kf[1][0], aq0, CINIT);
    e1 = MFMA(kf[1][1], aq1, e1);
    writeP(e0, e1, (char*)Ps[0]);
  }
  loadK(1);
  asm volatile("s_waitcnt lgkmcnt(0)" ::: "memory");
  __builtin_amdgcn_s_barrier();
  asm volatile("" ::: "memory");

  for (int it = 0; it < 64; ++it) {
    char* Prd = (char*)Ps[it & 1];
    char* Pwr = (char*)Ps[(it + 1) & 1];
    // P(t) frags for PV kc=0 — independent of the QK(t+1) chain below
    bf16x8 bp0[4];
#pragma unroll
    for (int nt = 0; nt < 4; ++nt)
      bp0[nt] = *(const bf16x8*)(Prd + ((((nt * 16 + ln) * 128 + quad * 16)) ^ swz));
    if (it < 63) {
      // QK(t+1) on prefetched kf
      __builtin_amdgcn_s_setprio(1);
      f32x4 e0 = MFMA(kf[0][0], aq0, CINIT);
      e0 = MFMA(kf[0][1], aq1, e0);
      f32x4 e1 = MFMA(kf[1][0], aq0, CINIT);
      e1 = MFMA(kf[1][1], aq1, e1);
      __builtin_amdgcn_s_setprio(0);
      if (it < 62) loadK(it + 2);
      writeP(e0, e1, Pwr);
    }
    // PV(t) kc=0
    __builtin_amdgcn_s_setprio(1);
#pragma unroll
    for (int mt = 0; mt < 2; ++mt)
#pragma unroll
      for (int nt = 0; nt < 4; ++nt)
        acc[mt][nt] = MFMA(vf[mt][0], bp0[nt], acc[mt][nt]);
    __builtin_amdgcn_s_setprio(0);
    // PV(t) kc=1
    bf16x8 bp1[4];
#pragma unroll
    for (int nt = 0; nt < 4; ++nt)
      bp1[nt] = *(const bf16x8*)(Prd + ((((nt * 16 + ln) * 128 + 64 + quad * 16)) ^ swz));
    __builtin_amdgcn_s_setprio(1);
#pragma unroll
    for (int mt = 0; mt < 2; ++mt)
#pragma unroll
      for (int nt = 0; nt < 4; ++nt)
        acc[mt][nt] = MFMA(vf[mt][1], bp1[nt], acc[mt][nt]);
    __builtin_amdgcn_s_setprio(0);
    if (it < 63) {
      loadV(it + 1);                      // vf dead after PV(t)
      asm volatile("s_waitcnt lgkmcnt(0)" ::: "memory");
      __builtin_amdgcn_s_barrier();
      asm volatile("" ::: "memory");
    }
  }

  // ---- S reduce (sum over quads = this wave's k range) + epilogue ----
  {
    float s = Sacc;
    s += __shfl_xor(s, 16);
    s += __shfl_xor(s, 32);
    if (quad == 0) Red[kh][qrow] = s;
  }
  __syncthreads();
  float rsv[4];
#pragma unroll
  for (int nt = 0; nt < 4; ++nt)
    rsv[nt] = 1.0f / (Red[0][nt * 16 + ln] + Red[1][nt * 16 + ln]);

  const float g = gamma[0];
#pragma unroll
  for (int mt = 0; mt < 2; ++mt) {
#pragma unroll
    for (int r = 0; r < 4; ++r) {
      const int ch = ch0 + w * 32 + mt * 16 + quad * 4 + r;
      const size_t base = ((size_t)b * C_ + ch) * HW_ + q0;
#pragma unroll
      for (int nt = 0; nt < 4; ++nt) {
        const size_t idx = base + nt * 16 + ln;
        out[idx] = g * (acc[mt][nt][r] * rsv[nt]) + fe[idx];
      }
    }
  }
}

// ---------------------------------------------------------------------------
extern "C" void kernel_launch(void* const* d_in, const int* in_sizes, int n_in,
                              void* d_out, int out_size, void* d_ws, size_t ws_size,
                              hipStream_t stream) {
  const float* fe    = (const float*)d_in[0];
  const float* total = (const float*)d_in[1];
  const float* Wq    = (const float*)d_in[2];
  const float* bq    = (const float*)d_in[3];
  const float* Wk    = (const float*)d_in[4];
  const float* bk    = (const float*)d_in[5];
  const float* Wv    = (const float*)d_in[6];
  const float* bv    = (const float*)d_in[7];
  const float* ht    = (const float*)d_in[8];
  const float* wt    = (const float*)d_in[9];
  const float* gamma = (const float*)d_in[10];
  float* out = (float*)d_out;

  // ws: Qhat 2MB | Khat 2MB | Vhat 16MB (fragment-major)
  unsigned short* Qh = (unsigned short*)d_ws;
  unsigned short* Kh = Qh + (size_t)B_ * HW_ * C8_;
  unsigned short* Vn = Kh + (size_t)B_ * HW_ * C8_;

  proj_kernel<<<dim3(64, B_), 640, 0, stream>>>(total, fe, Wq, bq, Wk, bk,
                                                Wv, bv, ht, wt, Qh, Kh, Vn);
  flash_kernel<<<dim3(512), 512, 0, stream>>>(Qh, Kh, Vn, fe, gamma, out);
}

// Round 6
// 221.710 us; speedup vs baseline: 1.0455x; 1.0455x over previous
//
#include <hip/hip_runtime.h>
#include <hip/hip_bf16.h>

#define B_   4
#define C_   512
#define C8_  64
#define HW_  4096

typedef short bf16x8 __attribute__((ext_vector_type(8)));
typedef float f32x4  __attribute__((ext_vector_type(4)));

__device__ __forceinline__ unsigned short f2bf(float f) {
  union { unsigned int i; float f; } x; x.f = f;
  unsigned int r = x.i + 0x7fffu + ((x.i >> 16) & 1u);   // RNE
  return (unsigned short)(r >> 16);
}

// packed f32x2 -> bf16x2 (RNE), single VALU op; no builtin on gfx950
__device__ __forceinline__ unsigned int cvtpk(float lo, float hi) {
  unsigned int r;
  asm("v_cvt_pk_bf16_f32 %0, %1, %2" : "=v"(r) : "v"(lo), "v"(hi));
  return r;
}

// 2^x, single transcendental op
__device__ __forceinline__ float fexp2(float x) {
  float r;
  asm("v_exp_f32 %0, %1" : "=v"(r) : "v"(x));
  return r;
}

#define MFMA(a, b, c) __builtin_amdgcn_mfma_f32_16x16x32_bf16((a), (b), (c), 0, 0, 0)

#define LOG2E 1.44269504f
#define NEG20LOG2E -28.8539008f   // -20*log2(e): folded softmax shift (C-init)

// ---------------------------------------------------------------------------
// Fragment-major workspace layouts (R8): every flash global load is one
// fully-contiguous 1KB wave load (lane*16B).
//  Q/K (64-col):  idx = (b*512 + (row>>4)*2 + (col>>5))*512
//                     + ((col>>3)&3)*128 + (row&15)*8 + (col&7)
//  V ([ch][m]):   idx = ((b*32 + (ch>>4))*128 + (m>>5))*512
//                     + ((m>>3)&3)*128 + (ch&15)*8 + (m&7)
//  Q is pre-scaled by log2e (flash uses v_exp_f32 with C-init -20*log2e).
// ---------------------------------------------------------------------------

// ---------------------------------------------------------------------------
// proj (R11, unchanged): merged Q|K|V, one block per (m-tile, b) = 256 blocks,
// 640 threads. Per kb LDS holds all 640 W rows + fe^T + total^T (110.6 KB).
// ---------------------------------------------------------------------------
__global__ __launch_bounds__(640) void proj_kernel(
    const float* __restrict__ total, const float* __restrict__ fe,
    const float* __restrict__ Wq, const float* __restrict__ bq,
    const float* __restrict__ Wk, const float* __restrict__ bk,
    const float* __restrict__ Wv, const float* __restrict__ bv,
    const float* __restrict__ ht, const float* __restrict__ wt,
    unsigned short* __restrict__ Qh, unsigned short* __restrict__ Kh,
    unsigned short* __restrict__ Vn) {
  __shared__ __align__(16) unsigned short Ws[640 * 72];   // rows: 0-63 Wq | 64-127 Wk | 128-639 Wv
  __shared__ __align__(16) unsigned short Xf[64 * 72];    // fe^T    [m][c]
  __shared__ __align__(16) unsigned short Xt[64 * 72];    // total^T [m][c]

  const int t = threadIdx.x;
  const int b = blockIdx.y;
  const int x = blockIdx.x;            // m-tile (= image row h, since W=64)
  const int m0 = x * 64;
  const int lane = t & 63, w = t >> 6, ln = lane & 15, quad = lane >> 4;

  const int c4 = t & 15;
  const int orow = t >> 4;             // 0..39

  f32x4 acc[4][4];                     // [ct(ch-tile)][mt(m-tile)]
#pragma unroll
  for (int ct = 0; ct < 4; ++ct)
#pragma unroll
    for (int mt = 0; mt < 4; ++mt) acc[ct][mt] = f32x4{0.f, 0.f, 0.f, 0.f};

  for (int kb = 0; kb < 8; ++kb) {
    const int c0 = kb * 64;
    // ---- stage W: 640 rows x 64 c, 16 tasks/thread ----
#pragma unroll
    for (int i = 0; i < 16; ++i) {
      const int o = i * 40 + orow;
      const float* src = (o < 64) ? &Wq[(size_t)o * C_]
                       : (o < 128) ? &Wk[(size_t)(o - 64) * C_]
                                   : &Wv[(size_t)(o - 128) * C_];
      f32x4 wv = *(const f32x4*)&src[c0 + c4 * 4];
      *(uint2*)&Ws[o * 72 + c4 * 4] =
          make_uint2(cvtpk(wv[0], wv[1]), cvtpk(wv[2], wv[3]));
    }
    // ---- stage X transposes: threads 0-255 -> fe^T, 256-511 -> total^T ----
    if (t < 512) {
      const int t2 = t & 255;
      const float* Xsrc = (t < 256) ? fe : total;
      unsigned short* Xdst = (t < 256) ? Xf : Xt;
      const int rc4 = t2 >> 4, mq = t2 & 15;
      f32x4 xv[4];
#pragma unroll
      for (int k = 0; k < 4; ++k)
        xv[k] = *(const f32x4*)&Xsrc[((size_t)b * C_ + c0 + rc4 * 4 + k) * HW_ + m0 + mq * 4];
#pragma unroll
      for (int j = 0; j < 4; ++j)
        *(uint2*)&Xdst[(mq * 4 + j) * 72 + rc4 * 4] =
            make_uint2(cvtpk(xv[0][j], xv[1][j]), cvtpk(xv[2][j], xv[3][j]));
    }
    __syncthreads();
    // ---- MFMA: wave w computes rows [w*64, w*64+64) x [m0, m0+64) ----
    const unsigned short* Xsel = (w == 0) ? Xt : Xf;
    bf16x8 aw[4][2], bx[4][2];
#pragma unroll
    for (int ct = 0; ct < 4; ++ct) {
      aw[ct][0] = *(const bf16x8*)&Ws[(w * 64 + ct * 16 + ln) * 72 + quad * 8];
      aw[ct][1] = *(const bf16x8*)&Ws[(w * 64 + ct * 16 + ln) * 72 + 32 + quad * 8];
    }
#pragma unroll
    for (int mt = 0; mt < 4; ++mt) {
      bx[mt][0] = *(const bf16x8*)&Xsel[(mt * 16 + ln) * 72 + quad * 8];
      bx[mt][1] = *(const bf16x8*)&Xsel[(mt * 16 + ln) * 72 + 32 + quad * 8];
    }
#pragma unroll
    for (int ct = 0; ct < 4; ++ct)
#pragma unroll
      for (int mt = 0; mt < 4; ++mt) {
        acc[ct][mt] = MFMA(aw[ct][0], bx[mt][0], acc[ct][mt]);
        acc[ct][mt] = MFMA(aw[ct][1], bx[mt][1], acc[ct][mt]);
      }
    __syncthreads();
  }

  // ---- epilogue: D row = ch (quad*4+r), D col = m (ln) ----
  if (w == 0) {
    // Q: out(m, o) fragment-major, val = (acc + bq)*log2e
#pragma unroll
    for (int ct = 0; ct < 4; ++ct)
#pragma unroll
      for (int mt = 0; mt < 4; ++mt)
#pragma unroll
        for (int r = 0; r < 4; ++r) {
          const int o = ct * 16 + quad * 4 + r;
          const float val = (acc[ct][mt][r] + bq[o]) * LOG2E;
          const size_t idx = ((size_t)b * 512 + (x * 4 + mt) * 2 + (ct >> 1)) * 512
                           + ((((ct & 1) << 1) | (quad >> 1))) * 128
                           + ln * 8 + ((quad & 1) << 2) + r;
          Qh[idx] = f2bf(val);
        }
  } else if (w == 1) {
    // K: + bias + positional (h = x, wloc = mt*16+ln)
#pragma unroll
    for (int ct = 0; ct < 4; ++ct)
#pragma unroll
      for (int mt = 0; mt < 4; ++mt)
#pragma unroll
        for (int r = 0; r < 4; ++r) {
          const int o = ct * 16 + quad * 4 + r;
          const float val = acc[ct][mt][r] + bk[o] + ht[o * 64 + x] + wt[o * 64 + mt * 16 + ln];
          const size_t idx = ((size_t)b * 512 + (x * 4 + mt) * 2 + (ct >> 1)) * 512
                           + ((((ct & 1) << 1) | (quad >> 1))) * 128
                           + ln * 8 + ((quad & 1) << 2) + r;
          Kh[idx] = f2bf(val);
        }
  } else {
    // V: ch = (w-2)*64 + ct*16 + quad*4 + r, fragment-major [ch][m]
#pragma unroll
    for (int ct = 0; ct < 4; ++ct) {
      const int cht = w * 4 - 8 + ct;
#pragma unroll
      for (int r = 0; r < 4; ++r) {
        const float bz = bv[cht * 16 + quad * 4 + r];
#pragma unroll
        for (int mt = 0; mt < 4; ++mt) {
          const size_t idx = (((size_t)b * 32 + cht) * 128 + (size_t)x * 2 + (mt >> 1)) * 512
                           + (((mt & 1) * 2) + (ln >> 3)) * 128 + (quad * 4 + r) * 8 + (ln & 7);
          Vn[idx] = f2bf(acc[ct][mt][r] + bz);
        }
      }
    }
  }
}

// ---------------------------------------------------------------------------
// flash R10->R12: q-tile 64 -> 128. grid 256 (1 block/CU), 512 thr, 8 waves.
// Wave w: QK for (qs=w&3: 32-q slice, kh=w>>2: 32-k half) = 8 MFMAs/iter;
// PV for ch slice w*32..+31 over all 128 q = 32 MFMAs/iter. K/V loads per
// iter UNCHANGED but serve 2x the output -> total L2 traffic halves
// (2.1 GB -> 1.05 GB/launch). Theory: VMEM request issue was the largest
// per-CU demand (~2048 of 3470 cyc/iter); now ~1024, balanced vs LDS ~1125.
// Same skewed pipeline {read P(t) || QK(t+1)+exp2+writeP(t+1)} then PV(t),
// 1 raw barrier/iter (lgkm-only drain), same P swizzle (row stride still
// 128B). acc[2][8]=64 VGPR -> launch_bounds(512,2) (8 waves/CU = 2/SIMD).
// ---------------------------------------------------------------------------
__global__ __launch_bounds__(512, 2) void flash_kernel(
    const unsigned short* __restrict__ Qh, const unsigned short* __restrict__ Kh,
    const unsigned short* __restrict__ Vn, const float* __restrict__ fe,
    const float* __restrict__ gamma, float* __restrict__ out) {
  __shared__ __align__(16) unsigned short Ps[2][128 * 64];   // 32 KB, swizzled
  __shared__ float Red[2][128];

  const int t = threadIdx.x;
  const int n = blockIdx.x;
  const int xcd = n & 7;                 // XCD swizzle: one (b, ch-half) per XCD
  const int b = xcd & 3;
  const int ch0 = (xcd >> 2) * 256;
  const int q0 = (n >> 3) * 128;
  const int lane = t & 63, w = t >> 6, ln = lane & 15, quad = lane >> 4;
  const int qs = w & 3;                  // 32-q slice for QK^T
  const int kh = w >> 2;                 // 32-k half for QK^T
  const int swz = (ln & 7) << 4;         // P LDS XOR swizzle (byte)

  const unsigned short* Qb = Qh + (size_t)b * 512 * 512;
  const unsigned short* Kb = Kh + (size_t)b * 512 * 512;
  const unsigned short* Vbase = Vn + ((size_t)b * 32 + (ch0 >> 4)) * (128 * 512);

  // Q B-fragments (pre-scaled by log2e): [sub q-16-tile][c-half]
  bf16x8 aq[2][2];
#pragma unroll
  for (int sub = 0; sub < 2; ++sub)
#pragma unroll
    for (int hf = 0; hf < 2; ++hf)
      aq[sub][hf] = *(const bf16x8*)
          &Qb[((size_t)((q0 >> 4) + qs * 2 + sub) * 2 + hf) * 512 + lane * 8];

  const f32x4 CINIT = {NEG20LOG2E, NEG20LOG2E, NEG20LOG2E, NEG20LOG2E};

  float Sacc0 = 0.f, Sacc1 = 0.f;        // softmax denom partials (sub 0/1)
  f32x4 acc[2][8];                       // [ch-subtile][q-subtile]
#pragma unroll
  for (int mt = 0; mt < 2; ++mt)
#pragma unroll
    for (int nt = 0; nt < 8; ++nt) acc[mt][nt] = f32x4{0.f, 0.f, 0.f, 0.f};

  bf16x8 kf[2][2];   // [k-16-tile][c-half], this wave's kh half only
  bf16x8 vf[2][2];   // [ch-16-tile][k-chunk], ch rows w*32 + mt*16 + ln

  auto loadK = [&](int it) {
#pragma unroll
    for (int nt = 0; nt < 2; ++nt)
#pragma unroll
      for (int hf = 0; hf < 2; ++hf)
        kf[nt][hf] = *(const bf16x8*)&Kb[((size_t)(it * 4 + kh * 2 + nt) * 2 + hf) * 512 + lane * 8];
  };
  auto loadV = [&](int it) {
#pragma unroll
    for (int mt = 0; mt < 2; ++mt)
#pragma unroll
      for (int kc = 0; kc < 2; ++kc)
        vf[mt][kc] = *(const bf16x8*)&Vbase[(((size_t)(w * 2 + mt)) * 128 + it * 2 + kc) * 512 + lane * 8];
  };

  const int qr0 = qs * 32 + ln;          // lane's q (sub 0); sub 1 = +16

  // QK for this wave's (kh, qs): E[32k][32q] as 4 f32x4, then exp2 + packed
  // bf16 stores. e(sub, kn): k = kh*32 + kn*16 + quad*4 + r, q = qr0 + sub*16.
  auto qkWrite = [&](char* Pw) {
    f32x4 e00 = MFMA(kf[0][0], aq[0][0], CINIT);
    e00 = MFMA(kf[0][1], aq[0][1], e00);
    f32x4 e01 = MFMA(kf[1][0], aq[0][0], CINIT);
    e01 = MFMA(kf[1][1], aq[0][1], e01);
    f32x4 e10 = MFMA(kf[0][0], aq[1][0], CINIT);
    e10 = MFMA(kf[0][1], aq[1][1], e10);
    f32x4 e11 = MFMA(kf[1][0], aq[1][0], CINIT);
    e11 = MFMA(kf[1][1], aq[1][1], e11);
#pragma unroll
    for (int kn = 0; kn < 2; ++kn) {
      const f32x4 ea = (kn == 0) ? e00 : e01;
      const float a0 = fexp2(ea[0]), a1 = fexp2(ea[1]);
      const float a2 = fexp2(ea[2]), a3 = fexp2(ea[3]);
      Sacc0 += (a0 + a1) + (a2 + a3);
      *(uint2*)(Pw + ((qr0 * 128 + kh * 64 + kn * 32 + quad * 8) ^ swz)) =
          make_uint2(cvtpk(a0, a1), cvtpk(a2, a3));
      const f32x4 eb = (kn == 0) ? e10 : e11;
      const float b0 = fexp2(eb[0]), b1 = fexp2(eb[1]);
      const float b2 = fexp2(eb[2]), b3 = fexp2(eb[3]);
      Sacc1 += (b0 + b1) + (b2 + b3);
      *(uint2*)(Pw + (((qr0 + 16) * 128 + kh * 64 + kn * 32 + quad * 8) ^ swz)) =
          make_uint2(cvtpk(b0, b1), cvtpk(b2, b3));
    }
  };

  loadK(0);
  loadV(0);

  // ---- prologue: QK(0) -> P(0) ----
  qkWrite((char*)Ps[0]);
  loadK(1);
  asm volatile("s_waitcnt lgkmcnt(0)" ::: "memory");
  __builtin_amdgcn_s_barrier();
  asm volatile("" ::: "memory");

  for (int it = 0; it < 64; ++it) {
    char* Prd = (char*)Ps[it & 1];
    char* Pwr = (char*)Ps[(it + 1) & 1];
    // P(t) frags for PV kc=0 — independent of the QK(t+1) chain below
    bf16x8 bp[8];
#pragma unroll
    for (int nt = 0; nt < 8; ++nt)
      bp[nt] = *(const bf16x8*)(Prd + ((((nt * 16 + ln) * 128 + quad * 16)) ^ swz));
    if (it < 63) {
      __builtin_amdgcn_s_setprio(1);
      qkWrite(Pwr);                       // QK(t+1) on prefetched kf
      __builtin_amdgcn_s_setprio(0);
      if (it < 62) loadK(it + 2);
    }
    // PV(t) kc=0
    __builtin_amdgcn_s_setprio(1);
#pragma unroll
    for (int mt = 0; mt < 2; ++mt)
#pragma unroll
      for (int nt = 0; nt < 8; ++nt)
        acc[mt][nt] = MFMA(vf[mt][0], bp[nt], acc[mt][nt]);
    __builtin_amdgcn_s_setprio(0);
    // PV(t) kc=1
#pragma unroll
    for (int nt = 0; nt < 8; ++nt)
      bp[nt] = *(const bf16x8*)(Prd + ((((nt * 16 + ln) * 128 + 64 + quad * 16)) ^ swz));
    __builtin_amdgcn_s_setprio(1);
#pragma unroll
    for (int mt = 0; mt < 2; ++mt)
#pragma unroll
      for (int nt = 0; nt < 8; ++nt)
        acc[mt][nt] = MFMA(vf[mt][1], bp[nt], acc[mt][nt]);
    __builtin_amdgcn_s_setprio(0);
    if (it < 63) {
      loadV(it + 1);                      // vf dead after PV(t)
      asm volatile("s_waitcnt lgkmcnt(0)" ::: "memory");
      __builtin_amdgcn_s_barrier();
      asm volatile("" ::: "memory");
    }
  }

  // ---- S reduce (sum over quads = this wave's k range) + epilogue ----
  {
    float s = Sacc0;
    s += __shfl_xor(s, 16);
    s += __shfl_xor(s, 32);
    if (quad == 0) Red[kh][qr0] = s;
    float s1 = Sacc1;
    s1 += __shfl_xor(s1, 16);
    s1 += __shfl_xor(s1, 32);
    if (quad == 0) Red[kh][qr0 + 16] = s1;
  }
  __syncthreads();
  float rsv[8];
#pragma unroll
  for (int nt = 0; nt < 8; ++nt)
    rsv[nt] = 1.0f / (Red[0][nt * 16 + ln] + Red[1][nt * 16 + ln]);

  const float g = gamma[0];
#pragma unroll
  for (int mt = 0; mt < 2; ++mt) {
#pragma unroll
    for (int r = 0; r < 4; ++r) {
      const int ch = ch0 + w * 32 + mt * 16 + quad * 4 + r;
      const size_t base = ((size_t)b * C_ + ch) * HW_ + q0;
#pragma unroll
      for (int nt = 0; nt < 8; ++nt) {
        const size_t idx = base + nt * 16 + ln;
        out[idx] = g * (acc[mt][nt][r] * rsv[nt]) + fe[idx];
      }
    }
  }
}

// ---------------------------------------------------------------------------
extern "C" void kernel_launch(void* const* d_in, const int* in_sizes, int n_in,
                              void* d_out, int out_size, void* d_ws, size_t ws_size,
                              hipStream_t stream) {
  const float* fe    = (const float*)d_in[0];
  const float* total = (const float*)d_in[1];
  const float* Wq    = (const float*)d_in[2];
  const float* bq    = (const float*)d_in[3];
  const float* Wk    = (const float*)d_in[4];
  const float* bk    = (const float*)d_in[5];
  const float* Wv    = (const float*)d_in[6];
  const float* bv    = (const float*)d_in[7];
  const float* ht    = (const float*)d_in[8];
  const float* wt    = (const float*)d_in[9];
  const float* gamma = (const float*)d_in[10];
  float* out = (float*)d_out;

  // ws: Qhat 2MB | Khat 2MB | Vhat 16MB (fragment-major)
  unsigned short* Qh = (unsigned short*)d_ws;
  unsigned short* Kh = Qh + (size_t)B_ * HW_ * C8_;
  unsigned short* Vn = Kh + (size_t)B_ * HW_ * C8_;

  proj_kernel<<<dim3(64, B_), 640, 0, stream>>>(total, fe, Wq, bq, Wk, bk,
                                                Wv, bv, ht, wt, Qh, Kh, Vn);
  flash_kernel<<<dim3(256), 512, 0, stream>>>(Qh, Kh, Vn, fe, gamma, out);
}